// Round 9
// baseline (50.357 us; speedup 1.0000x reference)
//
#include <hip/hip_runtime.h>

// PointPillarsScatter: out[b][c][y][x] = sum_{p: coords[p]=(b,_,y,x)} vf[p][c]
// B=4, C=64, NY=496, NX=432, P=48000. Output (B,C,NY,NX) f32 ~219 MB.
//
// Pipeline:
//   k0 init : hipMemsetAsync(head, 0xFF) -> -1 ints (~6.9 TB/s fill)
//   k1 build: per-pillar linked list via atomicExch (head/nxt in d_ws)
//   k2 gather: grid (837 tiles x 4 channel-groups); block = 1024 consecutive
//              cells x 16 channels. Per thread: 4 cells x 16 ch, direct int4
//              head load (distinct per thread), interleaved 4-chain walk,
//              float4 vf loads (exactly this block's 16 channels), 16 x
//              float4 stores -> 4KB contiguous per channel per block
//              (R8 lesson: gather is store-bound at ~5.3 TB/s with 1KB
//              channel-interleaved chunks; fill hits 6.9 TB/s with 4KB).

#define CC 64
#define GNY 496
#define GNX 432
#define S_CELLS (GNY * GNX)         // 214272 (divisible by 4)
#define NUM_CELLS (4 * S_CELLS)     // 857088
#define TILE_CELLS 1024
#define NTILES (NUM_CELLS / TILE_CELLS)  // 837 exactly

__global__ void pp_build(const int* __restrict__ coords,
                         int* __restrict__ head,
                         int* __restrict__ nxt,
                         int P) {
    int p = blockIdx.x * blockDim.x + threadIdx.x;
    if (p >= P) return;
    int4 c = ((const int4*)coords)[p];               // (b, z, y, x)
    int s = (c.x * GNY + c.z) * GNX + c.w;
    nxt[p] = atomicExch(&head[s], p);
}

__global__ __launch_bounds__(256)
void pp_gather(const float4* __restrict__ vf4,
               const int4* __restrict__ head4,
               const int* __restrict__ nxt,
               float* __restrict__ out) {
    int t = threadIdx.x;
    int tile = blockIdx.x;                 // 0..836: 1024 consecutive cells
    int cgb  = blockIdx.y;                 // 0..3: channels cgb*16 .. +15
    int s0 = tile * TILE_CELLS + t * 4;    // 4 consecutive cells (never straddle
    int b = s0 / S_CELLS;                  //  a batch: S_CELLS % 4 == 0)
    int r0 = s0 - b * S_CELLS;
    int cbase = cgb * 4;                   // float4-index offset into vf row

    // Distinct per-thread head load, fully coalesced (4KB per block).
    int4 h4 = head4[tile * 256 + t];
    int p0 = h4.x, p1 = h4.y, p2 = h4.z, p3 = h4.w;

    float acc[4][16];
    #pragma unroll
    for (int cell = 0; cell < 4; ++cell)
        #pragma unroll
        for (int i = 0; i < 16; ++i)
            acc[cell][i] = 0.f;

    // Interleaved chain walk (R8): all 4 cells advance in lock-step.
    while ((p0 >= 0) | (p1 >= 0) | (p2 >= 0) | (p3 >= 0)) {
        int q0 = p0, q1 = p1, q2 = p2, q3 = p3;
        if (q0 >= 0) p0 = nxt[q0];
        if (q1 >= 0) p1 = nxt[q1];
        if (q2 >= 0) p2 = nxt[q2];
        if (q3 >= 0) p3 = nxt[q3];
        if (q0 >= 0) {
            int pb = q0 * 16 + cbase;
            #pragma unroll
            for (int j = 0; j < 4; ++j) {
                float4 v = vf4[pb + j];
                acc[0][4*j+0] += v.x; acc[0][4*j+1] += v.y;
                acc[0][4*j+2] += v.z; acc[0][4*j+3] += v.w;
            }
        }
        if (q1 >= 0) {
            int pb = q1 * 16 + cbase;
            #pragma unroll
            for (int j = 0; j < 4; ++j) {
                float4 v = vf4[pb + j];
                acc[1][4*j+0] += v.x; acc[1][4*j+1] += v.y;
                acc[1][4*j+2] += v.z; acc[1][4*j+3] += v.w;
            }
        }
        if (q2 >= 0) {
            int pb = q2 * 16 + cbase;
            #pragma unroll
            for (int j = 0; j < 4; ++j) {
                float4 v = vf4[pb + j];
                acc[2][4*j+0] += v.x; acc[2][4*j+1] += v.y;
                acc[2][4*j+2] += v.z; acc[2][4*j+3] += v.w;
            }
        }
        if (q3 >= 0) {
            int pb = q3 * 16 + cbase;
            #pragma unroll
            for (int j = 0; j < 4; ++j) {
                float4 v = vf4[pb + j];
                acc[3][4*j+0] += v.x; acc[3][4*j+1] += v.y;
                acc[3][4*j+2] += v.z; acc[3][4*j+3] += v.w;
            }
        }
    }

    // Stores: per channel i, the block's 4 waves write 4 adjacent 1KB pieces
    // -> 4KB contiguous per channel plane per block.
    size_t outbase = (size_t)b * (CC * S_CELLS)
                   + (size_t)(cgb * 16) * S_CELLS + r0;
    #pragma unroll
    for (int i = 0; i < 16; ++i) {
        float4 o = make_float4(acc[0][i], acc[1][i], acc[2][i], acc[3][i]);
        *(float4*)&out[outbase + (size_t)i * S_CELLS] = o;
    }
}

extern "C" void kernel_launch(void* const* d_in, const int* in_sizes, int n_in,
                              void* d_out, int out_size, void* d_ws, size_t ws_size,
                              hipStream_t stream) {
    const float* vf     = (const float*)d_in[0];
    const int*   coords = (const int*)d_in[1];
    float*       out    = (float*)d_out;

    int P = in_sizes[1] / 4;                      // 48000

    size_t need = (size_t)(NUM_CELLS + P) * sizeof(int);
    if (ws_size < need) return;                   // cannot happen per harness sizing

    int* head = (int*)d_ws;
    int* nxt  = head + NUM_CELLS;

    // head[cell] = -1 via byte-fill 0xFF (graph-capturable, ~6.9 TB/s).
    hipMemsetAsync(head, 0xFF, (size_t)NUM_CELLS * sizeof(int), stream);
    pp_build<<<(P + 255) / 256, 256, 0, stream>>>(coords, head, nxt, P);
    pp_gather<<<dim3(NTILES, 4), 256, 0, stream>>>((const float4*)vf,
                                                   (const int4*)head, nxt, out);
}